// Round 20
// baseline (111.732 us; speedup 1.0000x reference)
//
#include <hip/hip_runtime.h>
#include <stdint.h>

#define H 32
#define HKV 8
#define D 128
#define SQ 1024
#define CTX 3072
#define SKV 4096
#define FP8_MAX_C 448.0f
#define EPS_C 1e-8f

typedef __attribute__((ext_vector_type(4))) float f32x4;
typedef __attribute__((ext_vector_type(8))) __bf16 bf16x8;
typedef __attribute__((ext_vector_type(8))) unsigned short u16x8;
typedef __attribute__((ext_vector_type(4))) unsigned short u16x4;

__device__ __forceinline__ unsigned short f2bf(float x) {
  unsigned int u = __builtin_bit_cast(unsigned int, x);
  u += 0x7fffu + ((u >> 16) & 1u);
  return (unsigned short)(u >> 16);
}

__device__ __forceinline__ f32x4 mfma16(bf16x8 a, bf16x8 b, f32x4 c) {
  return __builtin_amdgcn_mfma_f32_16x16x32_bf16(a, b, c, 0, 0, 0);
}

// async global->LDS, 16B per lane; dest = wave-uniform base + lane*16
__device__ __forceinline__ void gld16(const unsigned short* g, char* l) {
  __builtin_amdgcn_global_load_lds(
      (const __attribute__((address_space(1))) unsigned int*)g,
      (__attribute__((address_space(3))) unsigned int*)l, 16, 0, 0);
}

// explicit DMA drain before barrier (fixes replay-only race, R6/R7)
__device__ __forceinline__ void stage_sync() {
  asm volatile("s_waitcnt vmcnt(0)" ::: "memory");
  __builtin_amdgcn_sched_barrier(0);
  __syncthreads();
}

// ---- fused prep + absmax.
// Blocks 0..2047: k_comb[h][t][d] (reads+writes coalesced).
// Blocks 2048..2303: v_combT[h][d][t] via 128x128 LDS transpose so BOTH
// global sides are coalesced. New-token blocks also reduce absmax -> smax. ----
__global__ void prep_kv(const float* __restrict__ k,
                        const float* __restrict__ v,
                        const float* __restrict__ k_cache,
                        const float* __restrict__ v_cache,
                        const int* __restrict__ cache_slots,
                        unsigned short* __restrict__ k_comb,
                        unsigned short* __restrict__ v_combT,
                        unsigned int* __restrict__ smax) {
  __shared__ __align__(16) unsigned short vt[128 * 128];  // 32 KB
  float* red = (float*)vt;  // reduction scratch (aliased; sync'd below)
  float mx = 0.f;
  int sidx = -1;

  if (blockIdx.x < 2048) {
    const int tid = blockIdx.x * 256 + threadIdx.x;
    const int d8 = tid & 15;
    const int t = (tid >> 4) & (SKV - 1);
    const int h = tid >> 16;
    const int d0 = d8 * 8;
    const float* src;
    if (t < CTX) {
      int slot = cache_slots[t];
      src = k_cache + (size_t)slot * (HKV * D) + h * D + d0;
    } else {
      src = k + (size_t)(t - CTX) * (HKV * D) + h * D + d0;
      sidx = h;
    }
    float4 a = *reinterpret_cast<const float4*>(src);
    float4 bb = *reinterpret_cast<const float4*>(src + 4);
    u16x8 r;
    r[0] = f2bf(a.x);  r[1] = f2bf(a.y);
    r[2] = f2bf(a.z);  r[3] = f2bf(a.w);
    r[4] = f2bf(bb.x); r[5] = f2bf(bb.y);
    r[6] = f2bf(bb.z); r[7] = f2bf(bb.w);
    *reinterpret_cast<u16x8*>(k_comb + ((size_t)h * SKV + t) * D + d0) = r;
    if (sidx >= 0) {
      mx = fmaxf(fmaxf(fmaxf(fabsf(a.x), fabsf(a.y)),
                       fmaxf(fabsf(a.z), fabsf(a.w))),
                 fmaxf(fmaxf(fabsf(bb.x), fabsf(bb.y)),
                       fmaxf(fabsf(bb.z), fabsf(bb.w))));
    }
  } else {
    const int b = blockIdx.x - 2048;   // 0..255
    const int h = b >> 5;              // 0..7
    const int tb = (b & 31) * 128;     // CTX=3072 -> blocks 24..31 are new
    const int tx = threadIdx.x;
    const bool isnew = (tb >= CTX);
    if (isnew) sidx = 8 + h;
    // phase 1: read v[t][d] coalesced; LDS write with XOR swizzle
    // 128 t x 128 d / 4-per-thread = 4096 = 16 iters x 256 threads
#pragma unroll
    for (int j = 0; j < 16; ++j) {
      const int c = j * 256 + tx;
      const int t = c >> 5;
      const int d0 = (c & 31) * 4;
      const float* src;
      if (!isnew) {
        int slot = cache_slots[tb + t];
        src = v_cache + (size_t)slot * (HKV * D) + h * D + d0;
      } else {
        src = v + (size_t)(tb + t - CTX) * (HKV * D) + h * D + d0;
      }
      float4 a = *reinterpret_cast<const float4*>(src);
      if (isnew)
        mx = fmaxf(mx, fmaxf(fmaxf(fabsf(a.x), fabsf(a.y)),
                             fmaxf(fabsf(a.z), fabsf(a.w))));
      u16x4 r;
      r[0] = f2bf(a.x); r[1] = f2bf(a.y);
      r[2] = f2bf(a.z); r[3] = f2bf(a.w);
      const int y = ((t >> 3) & 15) << 3;
      *reinterpret_cast<u16x4*>(&vt[t * 128 + (d0 ^ y)]) = r;
    }
    __syncthreads();
    // phase 2: gather a d-row (8 t's) from swizzled LDS, write coalesced.
    // 128 d x 16 t-chunks = 2048 u16x8 = 8 iters x 256 threads  (R19 bug: 16)
#pragma unroll
    for (int j = 0; j < 8; ++j) {
      const int c = j * 256 + tx;
      const int d = c >> 4;              // 0..127
      const int t0 = (c & 15) * 8;
      const int y = ((t0 >> 3) & 15) << 3;  // constant over i (i<8)
      u16x8 r;
#pragma unroll
      for (int i = 0; i < 8; ++i) r[i] = vt[(t0 + i) * 128 + (d ^ y)];
      *reinterpret_cast<u16x8*>(v_combT + ((size_t)h * D + d) * SKV + tb + t0) = r;
    }
    __syncthreads();  // vt reads done before red[] aliasing below
  }

  if (sidx >= 0) {
    const int tx = threadIdx.x;
    red[tx] = mx;
    __syncthreads();
    for (int s = 128; s > 0; s >>= 1) {
      if (tx < s) red[tx] = fmaxf(red[tx], red[tx + s]);
      __syncthreads();
    }
    if (tx == 0) atomicMax(&smax[sidx], __float_as_uint(red[0]));
  }
}

#define LDBF(p) (*reinterpret_cast<const bf16x8*>(p))
#define Z4 ((f32x4){0.f, 0.f, 0.f, 0.f})

// exp2 one s-register; accumulate UNSCALED denom; then scale P by VS for PV
#define EXP4(SREG, P, RSV, VS)                                                 \
  {                                                                            \
    P[0] = __builtin_amdgcn_exp2f(SREG[0] - m);                                \
    P[1] = __builtin_amdgcn_exp2f(SREG[1] - m);                                \
    P[2] = __builtin_amdgcn_exp2f(SREG[2] - m);                                \
    P[3] = __builtin_amdgcn_exp2f(SREG[3] - m);                                \
    RSV += (P[0] + P[1]) + (P[2] + P[3]);                                      \
    P[0] *= VS; P[1] *= VS; P[2] *= VS; P[3] *= VS;                            \
  }

#define CVTPK(DST, LO, HI)                                                     \
  asm("v_cvt_pk_bf16_f32 %0, %1, %2" : "=v"(DST) : "v"(LO), "v"(HI));
#define SW32(A, B)                                                             \
  asm("v_permlane32_swap_b32 %0, %1" : "+v"(A), "+v"(B));
#define SW16(A, B)                                                             \
  asm("v_permlane16_swap_b32 %0, %1" : "+v"(A), "+v"(B));

// In-register P transpose for a 32-wide P row (R10-verified route)
#define PTRANS32(P0, P1, PF)                                                   \
  {                                                                            \
    unsigned int A_, Ap_, B_, Bp_;                                             \
    CVTPK(A_, P0[0], P0[1]) CVTPK(Ap_, P0[2], P0[3])                           \
    CVTPK(B_, P1[0], P1[1]) CVTPK(Bp_, P1[2], P1[3])                           \
    SW32(A_, B_) SW16(A_, B_)                                                  \
    SW32(Ap_, Bp_) SW16(Ap_, Bp_)                                              \
    union { unsigned int d[4]; bf16x8 v; } u_;                                 \
    u_.d[0] = A_; u_.d[1] = Ap_; u_.d[2] = B_; u_.d[3] = Bp_;                  \
    PF = u_.v;                                                                 \
  }

#define QKSF(SF, SA, SB)                                                       \
  {                                                                            \
    bf16x8 a0 = LDBF(kc + SF * 4096 + kx0);                                    \
    bf16x8 a1 = LDBF(kc + SF * 4096 + kx1);                                    \
    bf16x8 a2 = LDBF(kc + SF * 4096 + kx2);                                    \
    bf16x8 a3 = LDBF(kc + SF * 4096 + kx3);                                    \
    SA = mfma16(a0, qa0, SA); SA = mfma16(a1, qa1, SA);                        \
    SA = mfma16(a2, qa2, SA); SA = mfma16(a3, qa3, SA);                        \
    SB = mfma16(a0, qb0, SB); SB = mfma16(a1, qb1, SB);                        \
    SB = mfma16(a2, qb2, SB); SB = mfma16(a3, qb3, SB);                        \
  }

#define QLOADS                                                                 \
  {                                                                            \
    const float qs = 0.088388347648318447f * 1.4426950408889634f;              \
    const float* qpA = q + (size_t)(qbase + lo) * (H * D) + hqa * D;           \
    const float* qpB = qpA + D;                                                \
    _Pragma("unroll")                                                          \
    for (int ks_ = 0; ks_ < 4; ++ks_) {                                        \
      float4 a = *reinterpret_cast<const float4*>(qpA + ks_ * 32 + g * 8);     \
      float4 b = *reinterpret_cast<const float4*>(qpA + ks_ * 32 + g * 8 + 4); \
      union { unsigned short u[8]; bf16x8 v; } f;                              \
      f.u[0] = f2bf(a.x * qs); f.u[1] = f2bf(a.y * qs);                        \
      f.u[2] = f2bf(a.z * qs); f.u[3] = f2bf(a.w * qs);                        \
      f.u[4] = f2bf(b.x * qs); f.u[5] = f2bf(b.y * qs);                        \
      f.u[6] = f2bf(b.z * qs); f.u[7] = f2bf(b.w * qs);                        \
      if (ks_ == 0) qa0 = f.v; else if (ks_ == 1) qa1 = f.v;                   \
      else if (ks_ == 2) qa2 = f.v; else qa3 = f.v;                            \
      a = *reinterpret_cast<const float4*>(qpB + ks_ * 32 + g * 8);            \
      b = *reinterpret_cast<const float4*>(qpB + ks_ * 32 + g * 8 + 4);        \
      f.u[0] = f2bf(a.x * qs); f.u[1] = f2bf(a.y * qs);                        \
      f.u[2] = f2bf(a.z * qs); f.u[3] = f2bf(a.w * qs);                        \
      f.u[4] = f2bf(b.x * qs); f.u[5] = f2bf(b.y * qs);                        \
      f.u[6] = f2bf(b.z * qs); f.u[7] = f2bf(b.w * qs);                        \
      if (ks_ == 0) qb0 = f.v; else if (ks_ == 1) qb1 = f.v;                   \
      else if (ks_ == 2) qb2 = f.v; else qb3 = f.v;                            \
    }                                                                          \
  }

#define EPILOGUE(DSTEXPR)                                                      \
  lsa += __shfl_xor(lsa, 16); lsa += __shfl_xor(lsa, 32);                      \
  lsb += __shfl_xor(lsb, 16); lsb += __shfl_xor(lsb, 32);                      \
  float* dst = (DSTEXPR);                                                      \
  if (g == 0) {                                                                \
    float2 v;                                                                  \
    v.x = m; v.y = lsa;                                                        \
    *reinterpret_cast<float2*>(ml + ((size_t)part * SQ * H + (qbase + lo) * H + hqa) * 2) = v; \
    v.y = lsb;                                                                 \
    *reinterpret_cast<float2*>(ml + ((size_t)part * SQ * H + (qbase + lo) * H + hqa + 1) * 2) = v; \
  }                                                                            \
  _Pragma("unroll")                                                            \
  for (int r = 0; r < 4; ++r) {                                                \
    float* opa = dst + (size_t)(qbase + g * 4 + r) * (H * D) + hqa * D + lo;   \
    float* opb = opa + D;                                                      \
    opa[0 * 16] = aa0[r]; opb[0 * 16] = ab0[r];                                \
    opa[1 * 16] = aa1[r]; opb[1 * 16] = ab1[r];                                \
    opa[2 * 16] = aa2[r]; opb[2 * 16] = ab2[r];                                \
    opa[3 * 16] = aa3[r]; opb[3 * 16] = ab3[r];                                \
    opa[4 * 16] = aa4[r]; opb[4 * 16] = ab4[r];                                \
    opa[5 * 16] = aa5[r]; opb[5 * 16] = ab5[r];                                \
    opa[6 * 16] = aa6[r]; opb[6 * 16] = ab6[r];                                \
    opa[7 * 16] = aa7[r]; opb[7 * 16] = ab7[r];                                \
  }

#define RESCALE_ALL                                                            \
  if (!__all(pmax - m <= 8.f)) {                                               \
    float rm = fmaxf(pmax, __shfl_xor(pmax, 16));                              \
    rm = fmaxf(rm, __shfl_xor(rm, 32));                                        \
    float mn = fmaxf(m, rm);                                                   \
    float scl = __builtin_amdgcn_exp2f(m - mn);                                \
    lsa *= scl; lsb *= scl;                                                    \
    aa0 *= scl; aa1 *= scl; aa2 *= scl; aa3 *= scl;                            \
    aa4 *= scl; aa5 *= scl; aa6 *= scl; aa7 *= scl;                            \
    ab0 *= scl; ab1 *= scl; ab2 *= scl; ab3 *= scl;                            \
    ab4 *= scl; ab5 *= scl; ab6 *= scl; ab7 *= scl;                            \
    m = mn;                                                                    \
  }

// Stage 32x128 K tile (8KB) + 128x32 V^T tile (8KB), 256 threads x 2x16B.
#define STAGE32(TB, BUFO)                                                      \
  {                                                                            \
    _Pragma("unroll")                                                          \
    for (int j = 0; j < 2; ++j) {                                              \
      const int c = j * 256 + tid;                                             \
      const int r_ = c >> 4;                                                   \
      const int lc_ = (c & 15) ^ (r_ & 7);                                     \
      gld16(kb + (size_t)((TB) + r_) * D + lc_ * 8,                            \
            smem + (BUFO) + c * 16);                                           \
      const int dv_ = c >> 2;                                                  \
      const int cv_ = (c & 3) ^ ((dv_ >> 1) & 3);                              \
      gld16(vb + (size_t)dv_ * SKV + (TB) + cv_ * 8,                           \
            smem + (BUFO) + 8192 + c * 16);                                    \
    }                                                                          \
  }

// softmax of tile t -> pfa,pfb; ksel folds k_scale into ctx scores,
// vsel folds v_scale into P (after unscaled denom accumulation).
#define SOFTMAX32(KSEL, VSEL)                                                  \
  sa0 *= (KSEL); sa1 *= (KSEL); sb0 *= (KSEL); sb1 *= (KSEL);                  \
  float pmax = fmaxf(fmaxf(fmaxf(sa0[0], sa0[1]), fmaxf(sa0[2], sa0[3])),      \
                     fmaxf(fmaxf(sa1[0], sa1[1]), fmaxf(sa1[2], sa1[3])));     \
  pmax = fmaxf(pmax,                                                           \
               fmaxf(fmaxf(fmaxf(sb0[0], sb0[1]), fmaxf(sb0[2], sb0[3])),      \
                     fmaxf(fmaxf(sb1[0], sb1[1]), fmaxf(sb1[2], sb1[3]))));    \
  RESCALE_ALL                                                                  \
  float pa0[4], pa1[4], pb0[4], pb1[4];                                        \
  EXP4(sa0, pa0, lsa, (VSEL)) EXP4(sa1, pa1, lsa, (VSEL))                      \
  EXP4(sb0, pb0, lsb, (VSEL)) EXP4(sb1, pb1, lsb, (VSEL))                      \
  PTRANS32(pa0, pa1, pfa)                                                      \
  PTRANS32(pb0, pb1, pfb)

#define VLOAD                                                                  \
  vf0 = LDBF(vc + 0 * 1024 + vx); vf1 = LDBF(vc + 1 * 1024 + vx);              \
  vf2 = LDBF(vc + 2 * 1024 + vx); vf3 = LDBF(vc + 3 * 1024 + vx);              \
  vf4 = LDBF(vc + 4 * 1024 + vx); vf5 = LDBF(vc + 5 * 1024 + vx);              \
  vf6 = LDBF(vc + 6 * 1024 + vx); vf7 = LDBF(vc + 7 * 1024 + vx);

#define PVREG                                                                  \
  aa0 = mfma16(pfa_p, vf0, aa0); ab0 = mfma16(pfb_p, vf0, ab0);                \
  aa1 = mfma16(pfa_p, vf1, aa1); ab1 = mfma16(pfb_p, vf1, ab1);                \
  aa2 = mfma16(pfa_p, vf2, aa2); ab2 = mfma16(pfb_p, vf2, ab2);                \
  aa3 = mfma16(pfa_p, vf3, aa3); ab3 = mfma16(pfb_p, vf3, ab3);                \
  aa4 = mfma16(pfa_p, vf4, aa4); ab4 = mfma16(pfb_p, vf4, ab4);                \
  aa5 = mfma16(pfa_p, vf5, aa5); ab5 = mfma16(pfb_p, vf5, ab5);                \
  aa6 = mfma16(pfa_p, vf6, aa6); ab6 = mfma16(pfb_p, vf6, ab6);                \
  aa7 = mfma16(pfa_p, vf7, aa7); ab7 = mfma16(pfb_p, vf7, ab7);

// ---- flash attention, T15 att[2] pipeline: PV(t-1) overlaps QK(t).
// 4 waves x (2 heads x 16 q-rows), KVBLK=32, split-KV x2, grid 512.
// k/v scales applied in-kernel (ctx tiles = t<96). ----
__launch_bounds__(256, 2)
__global__ void attn_kernel(const float* __restrict__ q,
                            const unsigned short* __restrict__ k_comb,
                            const unsigned short* __restrict__ v_combT,
                            const unsigned int* __restrict__ smax,
                            float* __restrict__ out,
                            float* __restrict__ parts,
                            float* __restrict__ ml) {
  extern __shared__ __align__(16) char smem[];  // 2 x (8KB K + 8KB V)
  const int bid = blockIdx.x;
  const int hkv = bid & 7;            // XCD-aware
  const int qp_raw = (bid >> 3) & 31;
  const int part = bid >> 8;          // KV half
  const int qp = part ? (31 - qp_raw) : qp_raw;  // balance remap
  const int tid = threadIdx.x;
  const int wid = tid >> 6;
  const int l = tid & 63;
  const int lo = l & 15;
  const int g = l >> 4;
  const int qbase = qp * 32 + (wid >> 1) * 16;
  const int hqa = hkv * 4 + (wid & 1) * 2;
  const int n32 = 97 + qp;            // exact 32-tile count
  const int t0 = (part * n32) >> 1;
  const int t1 = ((part + 1) * n32) >> 1;

  const float kscale = fmaxf(__uint_as_float(smax[hkv]) / FP8_MAX_C, EPS_C);
  const float vscale = fmaxf(__uint_as_float(smax[8 + hkv]) / FP8_MAX_C, EPS_C);

  const unsigned short* kb = k_comb + (size_t)hkv * SKV * D;
  const unsigned short* vb = v_combT + (size_t)hkv * D * SKV;

  bf16x8 qa0, qa1, qa2, qa3, qb0, qb1, qb2, qb3;
  QLOADS

  f32x4 aa0 = Z4, aa1 = Z4, aa2 = Z4, aa3 = Z4;
  f32x4 aa4 = Z4, aa5 = Z4, aa6 = Z4, aa7 = Z4;
  f32x4 ab0 = Z4, ab1 = Z4, ab2 = Z4, ab3 = Z4;
  f32x4 ab4 = Z4, ab5 = Z4, ab6 = Z4, ab7 = Z4;
  float m = -1e30f;
  float lsa = 0.f, lsb = 0.f;

  const int xr = lo & 7;
  const int kx0 = ((0 + g) ^ xr) << 4;
  const int kx1 = ((4 + g) ^ xr) << 4;
  const int kx2 = ((8 + g) ^ xr) << 4;
  const int kx3 = ((12 + g) ^ xr) << 4;
  const int vx = ((g ^ ((lo >> 1) & 3))) << 4;
  const char* kbl = smem + lo * 256;
  const char* vbl = smem + 8192 + lo * 64;

  bf16x8 pfa_p, pfb_p;
  bf16x8 vf0, vf1, vf2, vf3, vf4, vf5, vf6, vf7;

  int cur = 0;
  STAGE32(t0 * 32, 0)
  stage_sync();

  // ---- peel tile t0: QK + softmax + V-load (no PV yet) ----
  {
    if (t0 + 1 < t1) STAGE32((t0 + 1) * 32, 16384)
    const char* kc = kbl;
    const char* vc = vbl;
    f32x4 sa0 = Z4, sa1 = Z4, sb0 = Z4, sb1 = Z4;
    __builtin_amdgcn_s_setprio(1);
    QKSF(0, sa0, sb0)
    QKSF(1, sa1, sb1)
    __builtin_amdgcn_s_setprio(0);
    bf16x8 pfa, pfb;
    const float ksel = (t0 < 96) ? kscale : 1.f;
    const float vsel = (t0 < 96) ? vscale : 1.f;
    SOFTMAX32(ksel, vsel)
    VLOAD
    pfa_p = pfa; pfb_p = pfb;
    stage_sync();
    cur = 1;
  }

  // ---- steady: QK(t) [LDS] || PV(t-1) [regs] -> softmax(t) -> V-load(t) ----
  for (int t = t0 + 1; t < t1; ++t) {
    if (t + 1 < t1) STAGE32((t + 1) * 32, (cur ^ 1) * 16384)

    const char* kc = kbl + cur * 16384;
    const char* vc = vbl + cur * 16384;

    f32x4 sa0 = Z4, sa1 = Z4, sb0 = Z4, sb1 = Z4;
    __builtin_amdgcn_s_setprio(1);
    QKSF(0, sa0, sb0)
    QKSF(1, sa1, sb1)
    PVREG
    __builtin_amdgcn_s_setprio(0);

    bf16x8 pfa, pfb;
    const float ksel = (t < 96) ? kscale : 1.f;
    const float vsel = (t < 96) ? vscale : 1.f;
    SOFTMAX32(ksel, vsel)
    VLOAD
    pfa_p = pfa; pfb_p = pfb;

    stage_sync();
    cur ^= 1;
  }

  // ---- drain: PV of the last tile ----
  PVREG

  EPILOGUE(part == 0 ? out : parts)
}

// ---- merge 2 KV-parts ----
__global__ void merge_kernel(float* __restrict__ out,
                             const float* __restrict__ parts,
                             const float* __restrict__ ml) {
  const int idx = blockIdx.x * 256 + threadIdx.x;
  const int h = (idx >> 5) & 31;
  const int qrow = idx >> 10;
  const float2* mp = (const float2*)ml;
  float2 A = mp[qrow * H + h];
  float2 B = mp[SQ * H + qrow * H + h];
  float mm = fmaxf(A.x, B.x);
  float wa = __builtin_amdgcn_exp2f(A.x - mm);
  float wb = __builtin_amdgcn_exp2f(B.x - mm);
  float inv = 1.f / (A.y * wa + B.y * wb);
  float4 oa = reinterpret_cast<float4*>(out)[idx];
  float4 ob = reinterpret_cast<const float4*>(parts)[idx];
  float4 r;
  r.x = (oa.x * wa + ob.x * wb) * inv;
  r.y = (oa.y * wa + ob.y * wb) * inv;
  r.z = (oa.z * wa + ob.z * wb) * inv;
  r.w = (oa.w * wa + ob.w * wb) * inv;
  reinterpret_cast<float4*>(out)[idx] = r;
}

extern "C" void kernel_launch(void* const* d_in, const int* in_sizes, int n_in,
                              void* d_out, int out_size, void* d_ws, size_t ws_size,
                              hipStream_t stream) {
  (void)in_sizes; (void)n_in; (void)out_size; (void)ws_size;
  const float* q = (const float*)d_in[0];
  const float* k = (const float*)d_in[1];
  const float* v = (const float*)d_in[2];
  const float* k_cache = (const float*)d_in[3];
  const float* v_cache = (const float*)d_in[4];
  const int* cache_slots = (const int*)d_in[6];
  float* out = (float*)d_out;

  unsigned int* smax = (unsigned int*)d_ws;                       // 16 u32
  unsigned short* k_comb = (unsigned short*)((char*)d_ws + 256);  // 8 MB
  unsigned short* v_combT = k_comb + (size_t)HKV * SKV * D;       // 8 MB
  float* parts = (float*)((char*)d_ws + 256 + (size_t)16 * 1024 * 1024); // 16 MB
  float* ml = parts + (size_t)SQ * H * D;                         // 512 KB

  hipMemsetAsync(smax, 0, 64, stream);
  prep_kv<<<2304, 256, 0, stream>>>(k, v, k_cache, v_cache, cache_slots,
                                    k_comb, v_combT, smax);
  attn_kernel<<<512, 256, 32768, stream>>>(q, k_comb, v_combT, smax, out,
                                           parts, ml);
  merge_kernel<<<4096, 256, 0, stream>>>(out, parts, ml);
}

// Round 21
// 108.749 us; speedup vs baseline: 1.0274x; 1.0274x over previous
//
#include <hip/hip_runtime.h>
#include <stdint.h>

#define H 32
#define HKV 8
#define D 128
#define SQ 1024
#define CTX 3072
#define SKV 4096
#define FP8_MAX_C 448.0f
#define EPS_C 1e-8f

typedef __attribute__((ext_vector_type(4))) float f32x4;
typedef __attribute__((ext_vector_type(8))) __bf16 bf16x8;
typedef __attribute__((ext_vector_type(8))) unsigned short u16x8;

__device__ __forceinline__ unsigned short f2bf(float x) {
  unsigned int u = __builtin_bit_cast(unsigned int, x);
  u += 0x7fffu + ((u >> 16) & 1u);
  return (unsigned short)(u >> 16);
}

__device__ __forceinline__ f32x4 mfma16(bf16x8 a, bf16x8 b, f32x4 c) {
  return __builtin_amdgcn_mfma_f32_16x16x32_bf16(a, b, c, 0, 0, 0);
}

// async global->LDS, 16B per lane; dest = wave-uniform base + lane*16
__device__ __forceinline__ void gld16(const unsigned short* g, char* l) {
  __builtin_amdgcn_global_load_lds(
      (const __attribute__((address_space(1))) unsigned int*)g,
      (__attribute__((address_space(3))) unsigned int*)l, 16, 0, 0);
}

// explicit DMA drain before barrier (fixes replay-only race, R6/R7)
__device__ __forceinline__ void stage_sync() {
  asm volatile("s_waitcnt vmcnt(0)" ::: "memory");
  __builtin_amdgcn_sched_barrier(0);
  __syncthreads();
}

// ---- fused prep + absmax: blocks 0..2047 build k_comb[h][t][d] (raw bf16);
//      2048..4095 build v_combT[h][d][t]. Blocks covering NEW tokens also
//      reduce |x| and atomicMax into smax[b] (k: b=h, v: b=8+h).
//      Scales are applied inside the attention kernel instead. ----
__global__ void prep_kv(const float* __restrict__ k,
                        const float* __restrict__ v,
                        const float* __restrict__ k_cache,
                        const float* __restrict__ v_cache,
                        const int* __restrict__ cache_slots,
                        unsigned short* __restrict__ k_comb,
                        unsigned short* __restrict__ v_combT,
                        unsigned int* __restrict__ smax) {
  __shared__ float red[256];
  float mx = 0.f;
  int sidx = -1;
  if (blockIdx.x < 2048) {
    const int tid = blockIdx.x * 256 + threadIdx.x;
    const int d8 = tid & 15;
    const int t = (tid >> 4) & (SKV - 1);
    const int h = tid >> 16;
    const int d0 = d8 * 8;
    const float* src;
    if (t < CTX) {
      int slot = cache_slots[t];
      src = k_cache + (size_t)slot * (HKV * D) + h * D + d0;
    } else {
      src = k + (size_t)(t - CTX) * (HKV * D) + h * D + d0;
      sidx = h;
    }
    float4 a = *reinterpret_cast<const float4*>(src);
    float4 bb = *reinterpret_cast<const float4*>(src + 4);
    u16x8 r;
    r[0] = f2bf(a.x);  r[1] = f2bf(a.y);
    r[2] = f2bf(a.z);  r[3] = f2bf(a.w);
    r[4] = f2bf(bb.x); r[5] = f2bf(bb.y);
    r[6] = f2bf(bb.z); r[7] = f2bf(bb.w);
    *reinterpret_cast<u16x8*>(k_comb + ((size_t)h * SKV + t) * D + d0) = r;
    if (sidx >= 0) {
      mx = fmaxf(fmaxf(fmaxf(fabsf(a.x), fabsf(a.y)),
                       fmaxf(fabsf(a.z), fabsf(a.w))),
                 fmaxf(fmaxf(fabsf(bb.x), fabsf(bb.y)),
                       fmaxf(fabsf(bb.z), fabsf(bb.w))));
    }
  } else {
    const int tid = (blockIdx.x - 2048) * 256 + threadIdx.x;
    const int d = tid & 127;
    const int t8 = (tid >> 7) & 511;
    const int h = tid >> 16;
    const int t0 = t8 * 8;
    u16x8 r;
    if (t0 < CTX) {
#pragma unroll
      for (int i = 0; i < 8; ++i) {
        int slot = cache_slots[t0 + i];
        r[i] = f2bf(v_cache[(size_t)slot * (HKV * D) + h * D + d]);
      }
    } else {
      sidx = 8 + h;
#pragma unroll
      for (int i = 0; i < 8; ++i) {
        float val = v[(size_t)(t0 + i - CTX) * (HKV * D) + h * D + d];
        mx = fmaxf(mx, fabsf(val));
        r[i] = f2bf(val);
      }
    }
    *reinterpret_cast<u16x8*>(v_combT + ((size_t)h * D + d) * SKV + t0) = r;
  }
  // block-level absmax reduce (sidx uniform per block; -1 => ctx block)
  if (sidx >= 0) {
    const int tx = threadIdx.x;
    red[tx] = mx;
    __syncthreads();
    for (int s = 128; s > 0; s >>= 1) {
      if (tx < s) red[tx] = fmaxf(red[tx], red[tx + s]);
      __syncthreads();
    }
    if (tx == 0) atomicMax(&smax[sidx], __float_as_uint(red[0]));
  }
}

#define LDBF(p) (*reinterpret_cast<const bf16x8*>(p))
#define Z4 ((f32x4){0.f, 0.f, 0.f, 0.f})

// exp2 one s-register; accumulate UNSCALED denom; then scale P by VS for PV
#define EXP4(SREG, P, RSV, VS)                                                 \
  {                                                                            \
    P[0] = __builtin_amdgcn_exp2f(SREG[0] - m);                                \
    P[1] = __builtin_amdgcn_exp2f(SREG[1] - m);                                \
    P[2] = __builtin_amdgcn_exp2f(SREG[2] - m);                                \
    P[3] = __builtin_amdgcn_exp2f(SREG[3] - m);                                \
    RSV += (P[0] + P[1]) + (P[2] + P[3]);                                      \
    P[0] *= VS; P[1] *= VS; P[2] *= VS; P[3] *= VS;                            \
  }

#define CVTPK(DST, LO, HI)                                                     \
  asm("v_cvt_pk_bf16_f32 %0, %1, %2" : "=v"(DST) : "v"(LO), "v"(HI));
#define SW32(A, B)                                                             \
  asm("v_permlane32_swap_b32 %0, %1" : "+v"(A), "+v"(B));
#define SW16(A, B)                                                             \
  asm("v_permlane16_swap_b32 %0, %1" : "+v"(A), "+v"(B));

// In-register P transpose for a 32-wide P row (R10-verified route)
#define PTRANS32(P0, P1, PF)                                                   \
  {                                                                            \
    unsigned int A_, Ap_, B_, Bp_;                                             \
    CVTPK(A_, P0[0], P0[1]) CVTPK(Ap_, P0[2], P0[3])                           \
    CVTPK(B_, P1[0], P1[1]) CVTPK(Bp_, P1[2], P1[3])                           \
    SW32(A_, B_) SW16(A_, B_)                                                  \
    SW32(Ap_, Bp_) SW16(Ap_, Bp_)                                              \
    union { unsigned int d[4]; bf16x8 v; } u_;                                 \
    u_.d[0] = A_; u_.d[1] = Ap_; u_.d[2] = B_; u_.d[3] = Bp_;                  \
    PF = u_.v;                                                                 \
  }

#define QKSF(SF, SA, SB)                                                       \
  {                                                                            \
    bf16x8 a0 = LDBF(kc + SF * 4096 + kx0);                                    \
    bf16x8 a1 = LDBF(kc + SF * 4096 + kx1);                                    \
    bf16x8 a2 = LDBF(kc + SF * 4096 + kx2);                                    \
    bf16x8 a3 = LDBF(kc + SF * 4096 + kx3);                                    \
    SA = mfma16(a0, qa0, SA); SA = mfma16(a1, qa1, SA);                        \
    SA = mfma16(a2, qa2, SA); SA = mfma16(a3, qa3, SA);                        \
    SB = mfma16(a0, qb0, SB); SB = mfma16(a1, qb1, SB);                        \
    SB = mfma16(a2, qb2, SB); SB = mfma16(a3, qb3, SB);                        \
  }

#define QLOADS                                                                 \
  {                                                                            \
    const float qs = 0.088388347648318447f * 1.4426950408889634f;              \
    const float* qpA = q + (size_t)(qbase + lo) * (H * D) + hqa * D;           \
    const float* qpB = qpA + D;                                                \
    _Pragma("unroll")                                                          \
    for (int ks_ = 0; ks_ < 4; ++ks_) {                                        \
      float4 a = *reinterpret_cast<const float4*>(qpA + ks_ * 32 + g * 8);     \
      float4 b = *reinterpret_cast<const float4*>(qpA + ks_ * 32 + g * 8 + 4); \
      union { unsigned short u[8]; bf16x8 v; } f;                              \
      f.u[0] = f2bf(a.x * qs); f.u[1] = f2bf(a.y * qs);                        \
      f.u[2] = f2bf(a.z * qs); f.u[3] = f2bf(a.w * qs);                        \
      f.u[4] = f2bf(b.x * qs); f.u[5] = f2bf(b.y * qs);                        \
      f.u[6] = f2bf(b.z * qs); f.u[7] = f2bf(b.w * qs);                        \
      if (ks_ == 0) qa0 = f.v; else if (ks_ == 1) qa1 = f.v;                   \
      else if (ks_ == 2) qa2 = f.v; else qa3 = f.v;                            \
      a = *reinterpret_cast<const float4*>(qpB + ks_ * 32 + g * 8);            \
      b = *reinterpret_cast<const float4*>(qpB + ks_ * 32 + g * 8 + 4);        \
      f.u[0] = f2bf(a.x * qs); f.u[1] = f2bf(a.y * qs);                        \
      f.u[2] = f2bf(a.z * qs); f.u[3] = f2bf(a.w * qs);                        \
      f.u[4] = f2bf(b.x * qs); f.u[5] = f2bf(b.y * qs);                        \
      f.u[6] = f2bf(b.z * qs); f.u[7] = f2bf(b.w * qs);                        \
      if (ks_ == 0) qb0 = f.v; else if (ks_ == 1) qb1 = f.v;                   \
      else if (ks_ == 2) qb2 = f.v; else qb3 = f.v;                            \
    }                                                                          \
  }

#define EPILOGUE(DSTEXPR)                                                      \
  lsa += __shfl_xor(lsa, 16); lsa += __shfl_xor(lsa, 32);                      \
  lsb += __shfl_xor(lsb, 16); lsb += __shfl_xor(lsb, 32);                      \
  float* dst = (DSTEXPR);                                                      \
  if (g == 0) {                                                                \
    float2 v;                                                                  \
    v.x = m; v.y = lsa;                                                        \
    *reinterpret_cast<float2*>(ml + ((size_t)part * SQ * H + (qbase + lo) * H + hqa) * 2) = v; \
    v.y = lsb;                                                                 \
    *reinterpret_cast<float2*>(ml + ((size_t)part * SQ * H + (qbase + lo) * H + hqa + 1) * 2) = v; \
  }                                                                            \
  _Pragma("unroll")                                                            \
  for (int r = 0; r < 4; ++r) {                                                \
    float* opa = dst + (size_t)(qbase + g * 4 + r) * (H * D) + hqa * D + lo;   \
    float* opb = opa + D;                                                      \
    opa[0 * 16] = aa0[r]; opb[0 * 16] = ab0[r];                                \
    opa[1 * 16] = aa1[r]; opb[1 * 16] = ab1[r];                                \
    opa[2 * 16] = aa2[r]; opb[2 * 16] = ab2[r];                                \
    opa[3 * 16] = aa3[r]; opb[3 * 16] = ab3[r];                                \
    opa[4 * 16] = aa4[r]; opb[4 * 16] = ab4[r];                                \
    opa[5 * 16] = aa5[r]; opb[5 * 16] = ab5[r];                                \
    opa[6 * 16] = aa6[r]; opb[6 * 16] = ab6[r];                                \
    opa[7 * 16] = aa7[r]; opb[7 * 16] = ab7[r];                                \
  }

#define RESCALE_ALL                                                            \
  if (!__all(pmax - m <= 8.f)) {                                               \
    float rm = fmaxf(pmax, __shfl_xor(pmax, 16));                              \
    rm = fmaxf(rm, __shfl_xor(rm, 32));                                        \
    float mn = fmaxf(m, rm);                                                   \
    float scl = __builtin_amdgcn_exp2f(m - mn);                                \
    lsa *= scl; lsb *= scl;                                                    \
    aa0 *= scl; aa1 *= scl; aa2 *= scl; aa3 *= scl;                            \
    aa4 *= scl; aa5 *= scl; aa6 *= scl; aa7 *= scl;                            \
    ab0 *= scl; ab1 *= scl; ab2 *= scl; ab3 *= scl;                            \
    ab4 *= scl; ab5 *= scl; ab6 *= scl; ab7 *= scl;                            \
    m = mn;                                                                    \
  }

// Stage 32x128 K tile (8KB) + 128x32 V^T tile (8KB), 256 threads x 2x16B.
#define STAGE32(TB, BUFO)                                                      \
  {                                                                            \
    _Pragma("unroll")                                                          \
    for (int j = 0; j < 2; ++j) {                                              \
      const int c = j * 256 + tid;                                             \
      const int r_ = c >> 4;                                                   \
      const int lc_ = (c & 15) ^ (r_ & 7);                                     \
      gld16(kb + (size_t)((TB) + r_) * D + lc_ * 8,                            \
            smem + (BUFO) + c * 16);                                           \
      const int dv_ = c >> 2;                                                  \
      const int cv_ = (c & 3) ^ ((dv_ >> 1) & 3);                              \
      gld16(vb + (size_t)dv_ * SKV + (TB) + cv_ * 8,                           \
            smem + (BUFO) + 8192 + c * 16);                                    \
    }                                                                          \
  }

// softmax of tile t -> pfa,pfb; ksel folds k_scale into ctx scores,
// vsel folds v_scale into P (after unscaled denom accumulation).
#define SOFTMAX32(KSEL, VSEL)                                                  \
  sa0 *= (KSEL); sa1 *= (KSEL); sb0 *= (KSEL); sb1 *= (KSEL);                  \
  float pmax = fmaxf(fmaxf(fmaxf(sa0[0], sa0[1]), fmaxf(sa0[2], sa0[3])),      \
                     fmaxf(fmaxf(sa1[0], sa1[1]), fmaxf(sa1[2], sa1[3])));     \
  pmax = fmaxf(pmax,                                                           \
               fmaxf(fmaxf(fmaxf(sb0[0], sb0[1]), fmaxf(sb0[2], sb0[3])),      \
                     fmaxf(fmaxf(sb1[0], sb1[1]), fmaxf(sb1[2], sb1[3]))));    \
  RESCALE_ALL                                                                  \
  float pa0[4], pa1[4], pb0[4], pb1[4];                                        \
  EXP4(sa0, pa0, lsa, (VSEL)) EXP4(sa1, pa1, lsa, (VSEL))                      \
  EXP4(sb0, pb0, lsb, (VSEL)) EXP4(sb1, pb1, lsb, (VSEL))                      \
  PTRANS32(pa0, pa1, pfa)                                                      \
  PTRANS32(pb0, pb1, pfb)

#define VLOAD                                                                  \
  vf0 = LDBF(vc + 0 * 1024 + vx); vf1 = LDBF(vc + 1 * 1024 + vx);              \
  vf2 = LDBF(vc + 2 * 1024 + vx); vf3 = LDBF(vc + 3 * 1024 + vx);              \
  vf4 = LDBF(vc + 4 * 1024 + vx); vf5 = LDBF(vc + 5 * 1024 + vx);              \
  vf6 = LDBF(vc + 6 * 1024 + vx); vf7 = LDBF(vc + 7 * 1024 + vx);

#define PVREG                                                                  \
  aa0 = mfma16(pfa_p, vf0, aa0); ab0 = mfma16(pfb_p, vf0, ab0);                \
  aa1 = mfma16(pfa_p, vf1, aa1); ab1 = mfma16(pfb_p, vf1, ab1);                \
  aa2 = mfma16(pfa_p, vf2, aa2); ab2 = mfma16(pfb_p, vf2, ab2);                \
  aa3 = mfma16(pfa_p, vf3, aa3); ab3 = mfma16(pfb_p, vf3, ab3);                \
  aa4 = mfma16(pfa_p, vf4, aa4); ab4 = mfma16(pfb_p, vf4, ab4);                \
  aa5 = mfma16(pfa_p, vf5, aa5); ab5 = mfma16(pfb_p, vf5, ab5);                \
  aa6 = mfma16(pfa_p, vf6, aa6); ab6 = mfma16(pfb_p, vf6, ab6);                \
  aa7 = mfma16(pfa_p, vf7, aa7); ab7 = mfma16(pfb_p, vf7, ab7);

// ---- flash attention, T15 att[2] pipeline: PV(t-1) overlaps QK(t).
// 4 waves x (2 heads x 16 q-rows), KVBLK=32, split-KV x2, grid 512.
// k/v scales applied in-kernel (ctx tiles = t<96). ----
__launch_bounds__(256, 2)
__global__ void attn_kernel(const float* __restrict__ q,
                            const unsigned short* __restrict__ k_comb,
                            const unsigned short* __restrict__ v_combT,
                            const unsigned int* __restrict__ smax,
                            float* __restrict__ out,
                            float* __restrict__ parts,
                            float* __restrict__ ml) {
  extern __shared__ __align__(16) char smem[];  // 2 x (8KB K + 8KB V)
  const int bid = blockIdx.x;
  const int hkv = bid & 7;            // XCD-aware
  const int qp_raw = (bid >> 3) & 31;
  const int part = bid >> 8;          // KV half
  const int qp = part ? (31 - qp_raw) : qp_raw;  // balance remap
  const int tid = threadIdx.x;
  const int wid = tid >> 6;
  const int l = tid & 63;
  const int lo = l & 15;
  const int g = l >> 4;
  const int qbase = qp * 32 + (wid >> 1) * 16;
  const int hqa = hkv * 4 + (wid & 1) * 2;
  const int n32 = 97 + qp;            // exact 32-tile count
  const int t0 = (part * n32) >> 1;
  const int t1 = ((part + 1) * n32) >> 1;

  const float kscale = fmaxf(__uint_as_float(smax[hkv]) / FP8_MAX_C, EPS_C);
  const float vscale = fmaxf(__uint_as_float(smax[8 + hkv]) / FP8_MAX_C, EPS_C);

  const unsigned short* kb = k_comb + (size_t)hkv * SKV * D;
  const unsigned short* vb = v_combT + (size_t)hkv * D * SKV;

  bf16x8 qa0, qa1, qa2, qa3, qb0, qb1, qb2, qb3;
  QLOADS

  f32x4 aa0 = Z4, aa1 = Z4, aa2 = Z4, aa3 = Z4;
  f32x4 aa4 = Z4, aa5 = Z4, aa6 = Z4, aa7 = Z4;
  f32x4 ab0 = Z4, ab1 = Z4, ab2 = Z4, ab3 = Z4;
  f32x4 ab4 = Z4, ab5 = Z4, ab6 = Z4, ab7 = Z4;
  float m = -1e30f;
  float lsa = 0.f, lsb = 0.f;

  const int xr = lo & 7;
  const int kx0 = ((0 + g) ^ xr) << 4;
  const int kx1 = ((4 + g) ^ xr) << 4;
  const int kx2 = ((8 + g) ^ xr) << 4;
  const int kx3 = ((12 + g) ^ xr) << 4;
  const int vx = ((g ^ ((lo >> 1) & 3))) << 4;
  const char* kbl = smem + lo * 256;
  const char* vbl = smem + 8192 + lo * 64;

  bf16x8 pfa_p, pfb_p;
  bf16x8 vf0, vf1, vf2, vf3, vf4, vf5, vf6, vf7;

  int cur = 0;
  STAGE32(t0 * 32, 0)
  stage_sync();

  // ---- peel tile t0: QK + softmax + V-load (no PV yet) ----
  {
    if (t0 + 1 < t1) STAGE32((t0 + 1) * 32, 16384)
    const char* kc = kbl;
    const char* vc = vbl;
    f32x4 sa0 = Z4, sa1 = Z4, sb0 = Z4, sb1 = Z4;
    __builtin_amdgcn_s_setprio(1);
    QKSF(0, sa0, sb0)
    QKSF(1, sa1, sb1)
    __builtin_amdgcn_s_setprio(0);
    bf16x8 pfa, pfb;
    const float ksel = (t0 < 96) ? kscale : 1.f;
    const float vsel = (t0 < 96) ? vscale : 1.f;
    SOFTMAX32(ksel, vsel)
    VLOAD
    pfa_p = pfa; pfb_p = pfb;
    stage_sync();
    cur = 1;
  }

  // ---- steady: QK(t) [LDS] || PV(t-1) [regs] -> softmax(t) -> V-load(t) ----
  for (int t = t0 + 1; t < t1; ++t) {
    if (t + 1 < t1) STAGE32((t + 1) * 32, (cur ^ 1) * 16384)

    const char* kc = kbl + cur * 16384;
    const char* vc = vbl + cur * 16384;

    f32x4 sa0 = Z4, sa1 = Z4, sb0 = Z4, sb1 = Z4;
    __builtin_amdgcn_s_setprio(1);
    QKSF(0, sa0, sb0)
    QKSF(1, sa1, sb1)
    PVREG
    __builtin_amdgcn_s_setprio(0);

    bf16x8 pfa, pfb;
    const float ksel = (t < 96) ? kscale : 1.f;
    const float vsel = (t < 96) ? vscale : 1.f;
    SOFTMAX32(ksel, vsel)
    VLOAD
    pfa_p = pfa; pfb_p = pfb;

    stage_sync();
    cur ^= 1;
  }

  // ---- drain: PV of the last tile ----
  PVREG

  EPILOGUE(part == 0 ? out : parts)
}

// ---- merge 2 KV-parts ----
__global__ void merge_kernel(float* __restrict__ out,
                             const float* __restrict__ parts,
                             const float* __restrict__ ml) {
  const int idx = blockIdx.x * 256 + threadIdx.x;
  const int h = (idx >> 5) & 31;
  const int qrow = idx >> 10;
  const float2* mp = (const float2*)ml;
  float2 A = mp[qrow * H + h];
  float2 B = mp[SQ * H + qrow * H + h];
  float mm = fmaxf(A.x, B.x);
  float wa = __builtin_amdgcn_exp2f(A.x - mm);
  float wb = __builtin_amdgcn_exp2f(B.x - mm);
  float inv = 1.f / (A.y * wa + B.y * wb);
  float4 oa = reinterpret_cast<float4*>(out)[idx];
  float4 ob = reinterpret_cast<const float4*>(parts)[idx];
  float4 r;
  r.x = (oa.x * wa + ob.x * wb) * inv;
  r.y = (oa.y * wa + ob.y * wb) * inv;
  r.z = (oa.z * wa + ob.z * wb) * inv;
  r.w = (oa.w * wa + ob.w * wb) * inv;
  reinterpret_cast<float4*>(out)[idx] = r;
}

extern "C" void kernel_launch(void* const* d_in, const int* in_sizes, int n_in,
                              void* d_out, int out_size, void* d_ws, size_t ws_size,
                              hipStream_t stream) {
  (void)in_sizes; (void)n_in; (void)out_size; (void)ws_size;
  const float* q = (const float*)d_in[0];
  const float* k = (const float*)d_in[1];
  const float* v = (const float*)d_in[2];
  const float* k_cache = (const float*)d_in[3];
  const float* v_cache = (const float*)d_in[4];
  const int* cache_slots = (const int*)d_in[6];
  float* out = (float*)d_out;

  unsigned int* smax = (unsigned int*)d_ws;                       // 16 u32
  unsigned short* k_comb = (unsigned short*)((char*)d_ws + 256);  // 8 MB
  unsigned short* v_combT = k_comb + (size_t)HKV * SKV * D;       // 8 MB
  float* parts = (float*)((char*)d_ws + 256 + (size_t)16 * 1024 * 1024); // 16 MB
  float* ml = parts + (size_t)SQ * H * D;                         // 512 KB

  hipMemsetAsync(smax, 0, 64, stream);
  prep_kv<<<4096, 256, 0, stream>>>(k, v, k_cache, v_cache, cache_slots,
                                    k_comb, v_combT, smax);
  attn_kernel<<<512, 256, 32768, stream>>>(q, k_comb, v_combT, smax, out,
                                           parts, ml);
  merge_kernel<<<4096, 256, 0, stream>>>(out, parts, ml);
}